// Round 5
// baseline (110.932 us; speedup 1.0000x reference)
//
#include <hip/hip_runtime.h>
#include <math.h>

// Problem constants (from reference)
#define BB     8192      // batch
#define DD     512       // embed dim
#define NEXP   16        // expansions per sample
#define TOPK   2048      // round(B * 0.25)
#define AUGX_ROWS (BB + TOPK * NEXP)              // 40960
#define AUGT_OFF  ((size_t)AUGX_ROWS * DD)        // 20971520
#define ISEXP_OFF (AUGT_OFF + AUGX_ROWS)          // 21012480

#define JCHUNK 256       // j-scores per rank block
#define COPY_BLOCKS 1024 // extra blocks fused into expand launch for x-copy

// ---------------------------------------------------------------------------
// Kernel 1: per-sample score in f64 (matches harness ordering at ties)
__global__ __launch_bounds__(64) void score_kernel(
    const float* __restrict__ x, const int* __restrict__ y,
    const float* __restrict__ prox, double* __restrict__ scores)
{
    int i = blockIdx.x;
    int lane = threadIdx.x;
    const float* xr = x + (size_t)i * DD;
    const float* pr = prox + (size_t)y[i] * DD;
    double sx = 0.0, sp = 0.0, dp = 0.0;
    #pragma unroll
    for (int e = 0; e < DD; e += 64) {
        float xv = xr[e + lane];
        float pv = pr[e + lane];
        sx += (double)xv * (double)xv;
        sp += (double)pv * (double)pv;
        dp += (double)xv * (double)pv;
    }
    #pragma unroll
    for (int off = 32; off > 0; off >>= 1) {
        sx += __shfl_down(sx, off);
        sp += __shfl_down(sp, off);
        dp += __shfl_down(dp, off);
    }
    if (lane == 0) {
        scores[i] = dp / (sqrt(sx + 1e-12) * sqrt(sp + 1e-12));
    }
}

// ---------------------------------------------------------------------------
// Kernel 2: partial rank accumulation; tie-break = jax.lax.top_k stability.
__global__ __launch_bounds__(256) void rank_kernel(
    const double* __restrict__ scores, int* __restrict__ ranks)
{
    __shared__ double ch[JCHUNK];
    int i = blockIdx.x * 256 + threadIdx.x;
    int jbase = blockIdx.y * JCHUNK;
    double si = scores[i];
    if (threadIdx.x < JCHUNK) ch[threadIdx.x] = scores[jbase + threadIdx.x];
    __syncthreads();
    int rank = 0;
    #pragma unroll 8
    for (int j = 0; j < JCHUNK; ++j) {
        double sj = ch[j];
        int jj = jbase + j;
        rank += (sj > si || (sj == si && jj < i)) ? 1 : 0;
    }
    atomicAdd(&ranks[i], rank);
}

// ---------------------------------------------------------------------------
// Kernel 3: ordered compaction (ascending sel[]), write is_expan floats.
__global__ __launch_bounds__(256) void compact_kernel(
    const int* __restrict__ ranks, int* __restrict__ sel, float* __restrict__ out)
{
    __shared__ int wsum[4];
    int t = threadIdx.x;
    int base = t * 32;
    int fl[32];
    int cnt = 0;
    for (int k = 0; k < 32; ++k) {
        fl[k] = (ranks[base + k] < TOPK) ? 1 : 0;
        cnt += fl[k];
    }
    int lane = t & 63, wave = t >> 6;
    int inc = cnt;
    #pragma unroll
    for (int off = 1; off < 64; off <<= 1) {
        int n = __shfl_up(inc, off);
        if (lane >= off) inc += n;
    }
    if (lane == 63) wsum[wave] = inc;
    __syncthreads();
    int wbase = 0;
    for (int w = 0; w < wave; ++w) wbase += wsum[w];
    int pos = wbase + inc - cnt;
    for (int k = 0; k < 32; ++k) {
        int i = base + k;
        out[ISEXP_OFF + i] = fl[k] ? 1.0f : 0.0f;
        if (fl[k]) sel[pos++] = i;
    }
}

// ---------------------------------------------------------------------------
__device__ inline void block_sum3(float& a, float& b, float& c, float* red, int t)
{
    #pragma unroll
    for (int off = 32; off > 0; off >>= 1) {
        a += __shfl_down(a, off);
        b += __shfl_down(b, off);
        c += __shfl_down(c, off);
    }
    __syncthreads();
    if ((t & 63) == 0) { int w = t >> 6; red[w] = a; red[4 + w] = b; red[8 + w] = c; }
    __syncthreads();
    a = red[0] + red[1] + red[2] + red[3];
    b = red[4] + red[5] + red[6] + red[7];
    c = red[8] + red[9] + red[10] + red[11];
}

__device__ inline float block_sum1(float v, float* red, int t)
{
    #pragma unroll
    for (int off = 32; off > 0; off >>= 1) v += __shfl_down(v, off);
    __syncthreads();
    if ((t & 63) == 0) red[t >> 6] = v;
    __syncthreads();
    return red[0] + red[1] + red[2] + red[3];
}

// ---------------------------------------------------------------------------
// Kernel 5: spherical expansion (blocks 0..TOPK-1) + raw-x copy (blocks >= TOPK).
// Expansion: coefficient-space orthogonalization via Cholesky of the 18x18
// Gram (A = L^-1), outputs via 16 back-substitutions C = bw_ext @ L^-1.
// All basis vectors live in LDS; registers stay small (no spills).
__global__ __launch_bounds__(256) void expand_kernel(
    const float* __restrict__ x, const int* __restrict__ y,
    const float* __restrict__ prox, const float* __restrict__ bwg,
    const float* __restrict__ rands, const int* __restrict__ sel,
    float* __restrict__ out)
{
    const int t = threadIdx.x;

    // ---- fused copy blocks: aug_x[0:B] = x, aug_t[0:B] = y
    if (blockIdx.x >= TOPK) {
        int cb = blockIdx.x - TOPK;
        int tid = cb * 256 + t;
        const float4* src = (const float4*)x;
        float4* dst = (float4*)out;
        const int nvec = BB * DD / 4;
        for (int idx = tid; idx < nvec; idx += COPY_BLOCKS * 256) dst[idx] = src[idx];
        if (tid < BB) out[AUGT_OFF + tid] = (float)y[tid];
        return;
    }

    __shared__ float Bm[18][DD];     // 36864 B: rows w, u1, r0..r15
    __shared__ float G[18][18];      // Gram matrix; rows 0..15 reused as C
    __shared__ float Ls[18][18];     // Cholesky factor (lower)
    __shared__ float invd[18];       // 1 / L[k][k]
    __shared__ float bws[16 * 17];   // bweights rows 1..16
    __shared__ float red[12];

    const int j = blockIdx.x;
    const int wave = t >> 6, lane = t & 63;
    const int s = sel[j];
    const int cls = y[s];

    // ---- stage 16 rand rows straight into LDS (transient registers only)
    {
        const float* rbase = rands + (size_t)j * NEXP * DD;
        #pragma unroll
        for (int i = 0; i < 8; ++i) {
            int row = 2 * i + (t >> 7);
            int col = (t & 127) * 4;
            float4 vv = *(const float4*)(rbase + (size_t)row * DD + col);
            *(float4*)&Bm[2 + row][col] = vv;
        }
    }
    // stage bweights rows 1..16 (linear: bwg[17 .. 17+272))
    for (int k = t; k < 16 * 17; k += 256) bws[k] = bwg[17 + k];

    float2 xv = ((const float2*)(x + (size_t)s * DD))[t];
    float2 pv = ((const float2*)(prox + (size_t)cls * DD))[t];

    float sx  = xv.x * xv.x + xv.y * xv.y;
    float sp  = pv.x * pv.x + pv.y * pv.y;
    float dxp = xv.x * pv.x + xv.y * pv.y;
    block_sum3(sx, sp, dxp, red, t);

    float xn = sqrtf(sx + 1e-12f), pn = sqrtf(sp + 1e-12f);
    float2 z  = { xv.x / xn, xv.y / xn };
    float2 w  = { pv.x / pn, pv.y / pn };
    float zw  = dxp / (xn * pn);
    float2 M  = { zw * w.x, zw * w.y };
    float2 r1 = { z.x - M.x, z.y - M.y };
    float r1sq = block_sum1(r1.x * r1.x + r1.y * r1.y, red, t);
    float r1n = sqrtf(r1sq);
    float inv1 = 1.0f / r1n;
    float2 u1 = { r1.x * inv1, r1.y * inv1 };

    ((float2*)Bm[0])[t] = w;
    ((float2*)Bm[1])[t] = u1;
    __syncthreads();

    // ---- Gram matrix: 171 independent 512-dots, wave-per-a-row.
    // float2 stride-2 reads: 4-way bank aliasing only.
    for (int a = wave; a < 18; a += 4) {
        float2 a0 = *(const float2*)&Bm[a][2 * lane];
        float2 a1 = *(const float2*)&Bm[a][2 * lane + 128];
        float2 a2 = *(const float2*)&Bm[a][2 * lane + 256];
        float2 a3 = *(const float2*)&Bm[a][2 * lane + 384];
        for (int b = a; b < 18; ++b) {
            float2 b0 = *(const float2*)&Bm[b][2 * lane];
            float2 b1 = *(const float2*)&Bm[b][2 * lane + 128];
            float2 b2 = *(const float2*)&Bm[b][2 * lane + 256];
            float2 b3 = *(const float2*)&Bm[b][2 * lane + 384];
            float p = a0.x * b0.x + a0.y * b0.y + a1.x * b1.x + a1.y * b1.y
                    + a2.x * b2.x + a2.y * b2.y + a3.x * b3.x + a3.y * b3.y;
            #pragma unroll
            for (int off = 32; off > 0; off >>= 1) p += __shfl_xor(p, off);
            if (lane == 0) { G[a][b] = p; G[b][a] = p; }
        }
    }
    __syncthreads();

    // ---- wave 0: Cholesky G = L L^T (lane = row), then 16 back-solves.
    if (wave == 0) {
        const int jl = (lane < 18) ? lane : 17;
        float Lrow[18];
        #pragma unroll
        for (int col = 0; col < 18; ++col) {
            float sv = G[jl][col];
            #pragma unroll
            for (int m = 0; m < col; ++m)
                sv -= Lrow[m] * Ls[col][m];       // broadcast read
            float scol = __shfl(sv, col);         // diag pivot
            float rsq = rsqrtf(scol);
            float lv = (jl >= col) ? sv * rsq : 0.0f;
            Lrow[col] = lv;
            if (lane < 18) Ls[jl][col] = lv;
            if (lane == 0) invd[col] = rsq;
        }
        // back-substitution: lane r solves L^T c = bw_ext_r  (r = 0..15)
        if (lane < 16) {
            float xreg[18];
            #pragma unroll
            for (int k = 17; k >= 0; --k) {
                float sv = (k == 0) ? 0.0f : bws[lane * 17 + (k - 1)];
                #pragma unroll
                for (int m = k + 1; m < 18; ++m)
                    sv -= Ls[m][k] * xreg[m];
                xreg[k] = sv * invd[k];
            }
            #pragma unroll
            for (int k = 0; k < 18; ++k) G[lane][k] = xreg[k];  // C rows 0..15
        }
    }
    __syncthreads();

    // ---- outputs: out_r = M + r1n * sum_j C[r][j] * b_j, 8-row chunks.
    float* orow = out + ((size_t)BB + (size_t)j * NEXP) * DD;
    #pragma unroll
    for (int half = 0; half < 2; ++half) {
        float acc0[8], acc1[8];
        #pragma unroll
        for (int r = 0; r < 8; ++r) { acc0[r] = 0.0f; acc1[r] = 0.0f; }
        #pragma unroll
        for (int jj = 0; jj < 18; ++jj) {
            float2 b = *(const float2*)&Bm[jj][2 * t];
            #pragma unroll
            for (int r = 0; r < 8; ++r) {
                float cc = G[half * 8 + r][jj];   // broadcast read
                acc0[r] += cc * b.x;
                acc1[r] += cc * b.y;
            }
        }
        #pragma unroll
        for (int r = 0; r < 8; ++r) {
            float2 ov = { M.x + r1n * acc0[r], M.y + r1n * acc1[r] };
            ((float2*)(orow + (size_t)(half * 8 + r) * DD))[t] = ov;
        }
    }

    if (t < NEXP) out[AUGT_OFF + BB + (size_t)j * NEXP + t] = (float)cls;
}

// ---------------------------------------------------------------------------
extern "C" void kernel_launch(void* const* d_in, const int* in_sizes, int n_in,
                              void* d_out, int out_size, void* d_ws, size_t ws_size,
                              hipStream_t stream)
{
    const float* x     = (const float*)d_in[0];   // [8192,512]
    const int*   y     = (const int*)d_in[1];     // [8192]
    const float* prox  = (const float*)d_in[2];   // [11318,512]
    const float* bw    = (const float*)d_in[3];   // [17,17]
    const float* rands = (const float*)d_in[4];   // [2048,16,512]
    float* out = (float*)d_out;

    double* scores = (double*)d_ws;                           // 64 KB
    int* ranks = (int*)((char*)d_ws + 65536);                 // 32 KB
    int* sel   = (int*)((char*)d_ws + 65536 + 32768);         // 8 KB

    hipMemsetAsync(ranks, 0, BB * sizeof(int), stream);

    score_kernel<<<BB, 64, 0, stream>>>(x, y, prox, scores);
    dim3 rgrid(BB / 256, BB / JCHUNK);
    rank_kernel<<<rgrid, 256, 0, stream>>>(scores, ranks);
    compact_kernel<<<1, 256, 0, stream>>>(ranks, sel, out);
    expand_kernel<<<TOPK + COPY_BLOCKS, 256, 0, stream>>>(x, y, prox, bw, rands, sel, out);
}

// Round 6
// 78.428 us; speedup vs baseline: 1.4144x; 1.4144x over previous
//
#include <hip/hip_runtime.h>
#include <math.h>

// Problem constants (from reference)
#define BB     8192      // batch
#define DD     512       // embed dim
#define NEXP   16        // expansions per sample
#define TOPK   2048      // round(B * 0.25)
#define AUGX_ROWS (BB + TOPK * NEXP)              // 40960
#define AUGT_OFF  ((size_t)AUGX_ROWS * DD)        // 20971520
#define ISEXP_OFF (AUGT_OFF + AUGX_ROWS)          // 21012480

#define JCHUNK 256       // j-scores per rank block
#define COPY_BLOCKS 1024 // extra blocks fused into expand launch for x-copy
#define BMP 520          // bf16 row pitch: 1040 B = 16B-aligned, bank step 4

typedef __attribute__((ext_vector_type(8)))  short bf16x8;
typedef __attribute__((ext_vector_type(16))) float f32x16;

__device__ inline ushort f2bf(float f) {   // RNE f32 -> bf16 bits
    uint u = __builtin_bit_cast(uint, f);
    return (ushort)((u + 0x7FFFu + ((u >> 16) & 1u)) >> 16);
}
__device__ inline float bf2f(ushort b) {
    uint u = ((uint)b) << 16;
    return __builtin_bit_cast(float, u);
}

// ---------------------------------------------------------------------------
// Kernel 1: per-sample score in f64 (matches harness ordering at ties)
__global__ __launch_bounds__(64) void score_kernel(
    const float* __restrict__ x, const int* __restrict__ y,
    const float* __restrict__ prox, double* __restrict__ scores)
{
    int i = blockIdx.x;
    int lane = threadIdx.x;
    const float* xr = x + (size_t)i * DD;
    const float* pr = prox + (size_t)y[i] * DD;
    double sx = 0.0, sp = 0.0, dp = 0.0;
    #pragma unroll
    for (int e = 0; e < DD; e += 64) {
        float xv = xr[e + lane];
        float pv = pr[e + lane];
        sx += (double)xv * (double)xv;
        sp += (double)pv * (double)pv;
        dp += (double)xv * (double)pv;
    }
    #pragma unroll
    for (int off = 32; off > 0; off >>= 1) {
        sx += __shfl_down(sx, off);
        sp += __shfl_down(sp, off);
        dp += __shfl_down(dp, off);
    }
    if (lane == 0) {
        scores[i] = dp / (sqrt(sx + 1e-12) * sqrt(sp + 1e-12));
    }
}

// ---------------------------------------------------------------------------
// Kernel 2: partial rank accumulation; tie-break = jax.lax.top_k stability.
__global__ __launch_bounds__(256) void rank_kernel(
    const double* __restrict__ scores, int* __restrict__ ranks)
{
    __shared__ double ch[JCHUNK];
    int i = blockIdx.x * 256 + threadIdx.x;
    int jbase = blockIdx.y * JCHUNK;
    double si = scores[i];
    if (threadIdx.x < JCHUNK) ch[threadIdx.x] = scores[jbase + threadIdx.x];
    __syncthreads();
    int rank = 0;
    #pragma unroll 8
    for (int j = 0; j < JCHUNK; ++j) {
        double sj = ch[j];
        int jj = jbase + j;
        rank += (sj > si || (sj == si && jj < i)) ? 1 : 0;
    }
    atomicAdd(&ranks[i], rank);
}

// ---------------------------------------------------------------------------
// Kernel 3: ordered compaction (ascending sel[]), write is_expan floats.
__global__ __launch_bounds__(256) void compact_kernel(
    const int* __restrict__ ranks, int* __restrict__ sel, float* __restrict__ out)
{
    __shared__ int wsum[4];
    int t = threadIdx.x;
    int base = t * 32;
    int fl[32];
    int cnt = 0;
    for (int k = 0; k < 32; ++k) {
        fl[k] = (ranks[base + k] < TOPK) ? 1 : 0;
        cnt += fl[k];
    }
    int lane = t & 63, wave = t >> 6;
    int inc = cnt;
    #pragma unroll
    for (int off = 1; off < 64; off <<= 1) {
        int n = __shfl_up(inc, off);
        if (lane >= off) inc += n;
    }
    if (lane == 63) wsum[wave] = inc;
    __syncthreads();
    int wbase = 0;
    for (int w = 0; w < wave; ++w) wbase += wsum[w];
    int pos = wbase + inc - cnt;
    for (int k = 0; k < 32; ++k) {
        int i = base + k;
        out[ISEXP_OFF + i] = fl[k] ? 1.0f : 0.0f;
        if (fl[k]) sel[pos++] = i;
    }
}

// ---------------------------------------------------------------------------
__device__ inline void block_sum3(float& a, float& b, float& c, float* red, int t)
{
    #pragma unroll
    for (int off = 32; off > 0; off >>= 1) {
        a += __shfl_down(a, off);
        b += __shfl_down(b, off);
        c += __shfl_down(c, off);
    }
    __syncthreads();
    if ((t & 63) == 0) { int w = t >> 6; red[w] = a; red[4 + w] = b; red[8 + w] = c; }
    __syncthreads();
    a = red[0] + red[1] + red[2] + red[3];
    b = red[4] + red[5] + red[6] + red[7];
    c = red[8] + red[9] + red[10] + red[11];
}

__device__ inline float block_sum1(float v, float* red, int t)
{
    #pragma unroll
    for (int off = 32; off > 0; off >>= 1) v += __shfl_down(v, off);
    __syncthreads();
    if ((t & 63) == 0) red[t >> 6] = v;
    __syncthreads();
    return red[0] + red[1] + red[2] + red[3];
}

// ---------------------------------------------------------------------------
// Kernel 5: spherical expansion (blocks 0..TOPK-1) + raw-x copy (blocks >= TOPK).
// Gram via MFMA (bf16 basis, exact f32 accumulate), orthogonalization via
// Cholesky (A = L^-1), outputs via 16 back-substitutions C = bw_ext @ L^-1.
__global__ __launch_bounds__(256) void expand_kernel(
    const float* __restrict__ x, const int* __restrict__ y,
    const float* __restrict__ prox, const float* __restrict__ bwg,
    const float* __restrict__ rands, const int* __restrict__ sel,
    float* __restrict__ out)
{
    const int t = threadIdx.x;

    // ---- fused copy blocks: aug_x[0:B] = x, aug_t[0:B] = y
    if (blockIdx.x >= TOPK) {
        int cb = blockIdx.x - TOPK;
        int tid = cb * 256 + t;
        const float4* src = (const float4*)x;
        float4* dst = (float4*)out;
        const int nvec = BB * DD / 4;
        for (int idx = tid; idx < nvec; idx += COPY_BLOCKS * 256) dst[idx] = src[idx];
        if (tid < BB) out[AUGT_OFF + tid] = (float)y[tid];
        return;
    }

    __shared__ ushort Bm[18][BMP];   // bf16 basis rows: w, u1, r0..r15 (18.7 KB)
    __shared__ float Gp[4][18][19];  // per-wave MFMA partials (5.5 KB)
    __shared__ float Gs[18][19];     // reduced Gram
    __shared__ float Ls[18][19];     // Cholesky factor (lower)
    __shared__ float Cs[16][18];     // output coefficient rows
    __shared__ float invd[18];       // 1 / L[k][k]
    __shared__ float bws[16 * 17];   // bweights rows 1..16
    __shared__ float red[12];

    const int j = blockIdx.x;
    const int wave = t >> 6, lane = t & 63;
    const int s = sel[j];
    const int cls = y[s];

    // ---- stage 16 rand rows into LDS as bf16 (transient registers only)
    {
        const float* rbase = rands + (size_t)j * NEXP * DD;
        #pragma unroll
        for (int i = 0; i < 8; ++i) {
            int row = 2 * i + (t >> 7);
            int col = (t & 127) * 4;
            float4 vv = *(const float4*)(rbase + (size_t)row * DD + col);
            ushort4 bv = { f2bf(vv.x), f2bf(vv.y), f2bf(vv.z), f2bf(vv.w) };
            *(ushort4*)&Bm[2 + row][col] = bv;
        }
    }
    // stage bweights rows 1..16 (linear: bwg[17 .. 17+272))
    for (int k = t; k < 16 * 17; k += 256) bws[k] = bwg[17 + k];

    float2 xv = ((const float2*)(x + (size_t)s * DD))[t];
    float2 pv = ((const float2*)(prox + (size_t)cls * DD))[t];

    float sx  = xv.x * xv.x + xv.y * xv.y;
    float sp  = pv.x * pv.x + pv.y * pv.y;
    float dxp = xv.x * pv.x + xv.y * pv.y;
    block_sum3(sx, sp, dxp, red, t);

    float xn = sqrtf(sx + 1e-12f), pn = sqrtf(sp + 1e-12f);
    float2 z  = { xv.x / xn, xv.y / xn };
    float2 w  = { pv.x / pn, pv.y / pn };
    float zw  = dxp / (xn * pn);
    float2 M  = { zw * w.x, zw * w.y };
    float2 r1 = { z.x - M.x, z.y - M.y };
    float r1sq = block_sum1(r1.x * r1.x + r1.y * r1.y, red, t);
    float r1n = sqrtf(r1sq);
    float inv1 = 1.0f / r1n;
    float2 u1 = { r1.x * inv1, r1.y * inv1 };

    { ushort2 wb = { f2bf(w.x),  f2bf(w.y)  }; *(ushort2*)&Bm[0][2 * t] = wb; }
    { ushort2 ub = { f2bf(u1.x), f2bf(u1.y) }; *(ushort2*)&Bm[1][2 * t] = ub; }
    __syncthreads();

    // ---- Gram via MFMA: G = Bm . Bm^T. A-frag == B-frag (same registers):
    // lane holds row (lane&31) [clamped], k = kbase + (lane>>5)*8 + i.
    {
        int row = lane & 31; if (row > 17) row = 17;
        int koff = (lane >> 5) * 8;
        const int kw = wave * 128;
        f32x16 acc = {0,0,0,0,0,0,0,0,0,0,0,0,0,0,0,0};
        #pragma unroll
        for (int stp = 0; stp < 8; ++stp) {
            bf16x8 av = *(const bf16x8*)&Bm[row][kw + stp * 16 + koff];
            acc = __builtin_amdgcn_mfma_f32_32x32x16_bf16(av, av, acc, 0, 0, 0);
        }
        // scatter D: col = lane&31, row = (reg&3) + 8*(reg>>2) + 4*(lane>>5)
        int col = lane & 31;
        if (col < 18) {
            #pragma unroll
            for (int rg = 0; rg < 16; ++rg) {
                int rr = (rg & 3) + 8 * (rg >> 2) + 4 * (lane >> 5);
                if (rr < 18) Gp[wave][rr][col] = acc[rg];
            }
        }
    }
    __syncthreads();

    // ---- reduce 4 wave-partials
    for (int e = t; e < 18 * 18; e += 256) {
        int r = e / 18, c = e - r * 18;
        Gs[r][c] = Gp[0][r][c] + Gp[1][r][c] + Gp[2][r][c] + Gp[3][r][c];
    }
    __syncthreads();

    // ---- wave 0: Cholesky Gs = L L^T (lane = row), then 16 back-solves.
    if (wave == 0) {
        const int jl = (lane < 18) ? lane : 17;
        float Lrow[18];
        #pragma unroll
        for (int col = 0; col < 18; ++col) {
            float sv = Gs[jl][col];
            #pragma unroll
            for (int m = 0; m < col; ++m)
                sv -= Lrow[m] * Ls[col][m];       // broadcast read
            float scol = __shfl(sv, col);         // diag pivot
            float rsq = rsqrtf(scol);
            float lv = (jl >= col) ? sv * rsq : 0.0f;
            Lrow[col] = lv;
            if (lane < 18) Ls[jl][col] = lv;
            if (lane == 0) invd[col] = rsq;
        }
        // back-substitution: lane r solves L^T c = bw_ext_r  (r = 0..15)
        if (lane < 16) {
            float xreg[18];
            #pragma unroll
            for (int k = 17; k >= 0; --k) {
                float sv = (k == 0) ? 0.0f : bws[lane * 17 + (k - 1)];
                #pragma unroll
                for (int m = k + 1; m < 18; ++m)
                    sv -= Ls[m][k] * xreg[m];
                xreg[k] = sv * invd[k];
            }
            #pragma unroll
            for (int k = 0; k < 18; ++k) Cs[lane][k] = xreg[k];
        }
    }
    __syncthreads();

    // ---- outputs: out_r = M + r1n * sum_j C[r][j] * b_j, 8-row chunks.
    float* orow = out + ((size_t)BB + (size_t)j * NEXP) * DD;
    #pragma unroll
    for (int half = 0; half < 2; ++half) {
        float acc0[8], acc1[8];
        #pragma unroll
        for (int r = 0; r < 8; ++r) { acc0[r] = 0.0f; acc1[r] = 0.0f; }
        #pragma unroll
        for (int jj = 0; jj < 18; ++jj) {
            float bx = bf2f(Bm[jj][2 * t]);
            float by = bf2f(Bm[jj][2 * t + 1]);
            #pragma unroll
            for (int r = 0; r < 8; ++r) {
                float cc = Cs[half * 8 + r][jj];  // broadcast read
                acc0[r] += cc * bx;
                acc1[r] += cc * by;
            }
        }
        #pragma unroll
        for (int r = 0; r < 8; ++r) {
            float2 ov = { M.x + r1n * acc0[r], M.y + r1n * acc1[r] };
            ((float2*)(orow + (size_t)(half * 8 + r) * DD))[t] = ov;
        }
    }

    if (t < NEXP) out[AUGT_OFF + BB + (size_t)j * NEXP + t] = (float)cls;
}

// ---------------------------------------------------------------------------
extern "C" void kernel_launch(void* const* d_in, const int* in_sizes, int n_in,
                              void* d_out, int out_size, void* d_ws, size_t ws_size,
                              hipStream_t stream)
{
    const float* x     = (const float*)d_in[0];   // [8192,512]
    const int*   y     = (const int*)d_in[1];     // [8192]
    const float* prox  = (const float*)d_in[2];   // [11318,512]
    const float* bw    = (const float*)d_in[3];   // [17,17]
    const float* rands = (const float*)d_in[4];   // [2048,16,512]
    float* out = (float*)d_out;

    double* scores = (double*)d_ws;                           // 64 KB
    int* ranks = (int*)((char*)d_ws + 65536);                 // 32 KB
    int* sel   = (int*)((char*)d_ws + 65536 + 32768);         // 8 KB

    hipMemsetAsync(ranks, 0, BB * sizeof(int), stream);

    score_kernel<<<BB, 64, 0, stream>>>(x, y, prox, scores);
    dim3 rgrid(BB / 256, BB / JCHUNK);
    rank_kernel<<<rgrid, 256, 0, stream>>>(scores, ranks);
    compact_kernel<<<1, 256, 0, stream>>>(ranks, sel, out);
    expand_kernel<<<TOPK + COPY_BLOCKS, 256, 0, stream>>>(x, y, prox, bw, rands, sel, out);
}